// Round 4
// baseline (1116.321 us; speedup 1.0000x reference)
//
#include <hip/hip_runtime.h>
#include <math.h>

// Problem constants
#define NXg 128
#define NYg 128
#define Pg  (NXg*NYg)      // 16384 pixels
#define Bq  64             // batch
#define Wd  64             // WIDTH (channels)
#define NKX 24             // kept kx rows: 0..11 and 116..127
#define NMODE (NKX*12)     // 288
#define PI2_128 0.04908738521234052f   // 2*pi/128

typedef _Float16 f16x8 __attribute__((ext_vector_type(8)));
typedef float    f32x4 __attribute__((ext_vector_type(4)));

// ---------------- workspace layout ----------------
// fp32 region (float offsets):
#define OFF_T2C 0
#define OFF_T2S (OFF_T2C + 24*128)
#define OFF_VAL (OFF_T2S + 24*128)
#define OFF_CNT (OFF_VAL + Bq*Pg)
#define OFF_XFR (OFF_CNT + Bq*Pg)
#define OFF_XFI (OFF_XFR + Bq*Wd*NMODE)
#define OFF_OFR (OFF_XFI + Bq*Wd*NMODE)
#define OFF_OFI (OFF_OFR + Bq*Wd*NMODE)
#define F32_END (OFF_OFI + Bq*Wd*NMODE)
// fp16 region (half offsets from (W + F32_END)):
#define H_T1E  0                         // T1e  [t=32][y=128]  (0..11 cos, 12..23 -sin, 24..31 zero)
#define H_T1ET (H_T1E + 32*128)          // T1eT [y=128][t=32]  transposed copy
#define H_A2   (H_T1ET + 128*32)         // A2   [48][256] stage-B DFT matrix
#define H_YG   (H_A2 + 48*256)           // Yg   [b][c][x][t=24] fp16, 25 MB
#define H_X    (H_YG + (size_t)Bq*Wd*128*24)  // x  [b][x][y][c] fp16, 134 MB

// ---------------- twiddle tables ----------------
__global__ void k_tables(float* T2c, float* T2s, _Float16* T1e_g, _Float16* T1eT_g, _Float16* A2_g) {
    int t = blockIdx.x * blockDim.x + threadIdx.x;   // 0..12287
    if (t < 24*128) {
        int kxi = t >> 7, xx = t & 127;
        int kx = (kxi < 12) ? kxi : (104 + kxi);   // 116..127
        float th = (float)((kx * xx) & 127) * PI2_128;
        T2c[t] = cosf(th);
        T2s[t] = sinf(th);
    }
    if (t < 32*128) {
        // T1e [r][y]
        int r = t >> 7, y = t & 127;
        float v = 0.f;
        if (r < 12)      v =  cosf((float)((r * y) & 127) * PI2_128);
        else if (r < 24) v = -sinf((float)(((r-12) * y) & 127) * PI2_128);
        T1e_g[t] = (_Float16)v;
        // T1eT [y][r]
        int y2 = t >> 5, r2 = t & 31;
        float v2 = 0.f;
        if (r2 < 12)      v2 =  cosf((float)((r2 * y2) & 127) * PI2_128);
        else if (r2 < 24) v2 = -sinf((float)(((r2-12) * y2) & 127) * PI2_128);
        T1eT_g[t] = (_Float16)v2;
    }
    if (t < 48*256) {
        int m = t >> 8, k = t & 255;
        int x = k & 127;
        int hi = (k >= 128);
        float v;
        if (m < 24) {
            int kx = (m < 12) ? m : (104 + m);
            float th = (float)((kx * x) & 127) * PI2_128;
            v = hi ? sinf(th) : cosf(th);
        } else {
            int mm = m - 24;
            int kx = (mm < 12) ? mm : (104 + mm);
            float th = (float)((kx * x) & 127) * PI2_128;
            v = hi ? cosf(th) : -sinf(th);
        }
        A2_g[t] = (_Float16)v;
    }
}

// ---------------- sparse scatter ----------------
__global__ void k_scatter(const float* __restrict__ xyt, const float* __restrict__ obs_c,
                          const float* __restrict__ obs_v, const int* __restrict__ nb,
                          const int* __restrict__ siy, const int* __restrict__ six,
                          float* val, float* cnt) {
    int t = blockIdx.x * 64 + threadIdx.x;   // 4096 = B*K
    int b = t >> 6;
    int id = nb[t];
    int sid = id / 50;                       // NT = 50
    float tq = xyt[b*3 + 2];
    float w = expf(-0.1f * fabsf(obs_c[id*3 + 2] - tq));
    int lin = siy[sid] * NYg + six[sid];
    atomicAdd(&val[b*Pg + lin], obs_v[id] * w);
    atomicAdd(&cnt[b*Pg + lin], w);
}

// ---------------- shared epilogue: coalesced x store + stage-A y-DFT + Yg store --------
__device__ __forceinline__ void epilogue_store(
    const _Float16 (*Xn)[104], const _Float16 (*Ot)[136], const _Float16 (*T1eR)[136],
    _Float16* __restrict__ xrow, _Float16* __restrict__ Yg, int b, int row, int tid)
{
    int wave = tid >> 6, lane = tid & 63;
    int l15 = lane & 15, quad = lane >> 4;
    // coalesced activation store: [y][c] contiguous
    float4* xr4 = (float4*)xrow;
    for (int i = tid; i < 1024; i += 256) {
        int y = i >> 3, cb = i & 7;
        xr4[i] = *(const float4*)&Xn[y][cb*8];
    }
    // stage A: Yk[o][t] = sum_y Ot[o][y] * T1e[t][y]   (M=64 o, N=24 t, K=128 y)
    f16x8 af[4];
    #pragma unroll
    for (int q = 0; q < 4; q++)
        af[q] = *(const f16x8*)&Ot[wave*16 + l15][q*32 + quad*8];
    #pragma unroll
    for (int nt2 = 0; nt2 < 2; nt2++) {
        f32x4 acc = {0.f,0.f,0.f,0.f};
        #pragma unroll
        for (int q = 0; q < 4; q++) {
            f16x8 bf = *(const f16x8*)&T1eR[nt2*16 + l15][q*32 + quad*8];
            acc = __builtin_amdgcn_mfma_f32_16x16x32_f16(af[q], bf, acc, 0, 0, 0);
        }
        int t = nt2*16 + l15;
        if (t < 24) {
            #pragma unroll
            for (int r = 0; r < 4; r++) {
                int o = wave*16 + quad*4 + r;
                Yg[((size_t)(b*64 + o)*128 + row)*24 + t] = (_Float16)acc[r];
            }
        }
    }
}

// ---------------- fc0 fused with y-DFT ----------------
// grid: (128 rows, Bq), block 256
__global__ __launch_bounds__(256) void k_fc0y(const float* __restrict__ val, const float* __restrict__ cnt,
                      const float* __restrict__ xg, const float* __restrict__ yg,
                      const float* __restrict__ w, const float* __restrict__ bb,
                      const _Float16* __restrict__ T1e_g,
                      _Float16* __restrict__ xh, _Float16* __restrict__ Yg) {
    __shared__ _Float16 Xn[128][104];
    __shared__ _Float16 Ot[64][136];
    __shared__ _Float16 T1eR[32][136];
    __shared__ float gl[128], a1l[128], a2l[128];
    __shared__ float w0[64], w1[64], w2[64], b0[64];
    int row = blockIdx.x, b = blockIdx.y;
    int tid = threadIdx.x;
    if (tid < 128) {
        int p = row*128 + tid;
        float c = cnt[(size_t)b*Pg + p];
        float v = val[(size_t)b*Pg + p];
        gl[tid]  = (c > 0.f) ? v / fmaxf(c, 1e-6f) : 0.f;
        a1l[tid] = xg[p];
        a2l[tid] = yg[p];
    }
    if (tid < 64) {
        w0[tid] = w[tid]; w1[tid] = w[64+tid]; w2[tid] = w[128+tid]; b0[tid] = bb[tid];
    }
    const float4* t1p = (const float4*)T1e_g;
    for (int i = tid; i < 512; i += 256) {
        int t = i >> 4, seg = i & 15;
        *(float4*)&T1eR[t][seg*8] = t1p[i];
    }
    __syncthreads();
    {
        int y = tid & 127, og = tid >> 7;
        float g = gl[y], a1 = a1l[y], a2 = a2l[y];
        #pragma unroll 8
        for (int j = 0; j < 32; j++) {
            int o = og*32 + j;
            float v = g*w0[o] + a1*w1[o] + a2*w2[o] + b0[o];
            _Float16 h = (_Float16)v;
            Xn[y][o] = h;
            Ot[o][y] = h;
        }
    }
    __syncthreads();
    _Float16* xrow = xh + (size_t)(b*128 + row) * 128 * 64;
    epilogue_store(Xn, Ot, T1eR, xrow, Yg, b, row, tid);
}

// ---------------- sB: stage-B x-DFT (Yg -> xf) via MFMA ----------------
// grid: Bq*Wd, block 256. XF(48m x 12ky) = A2(48x256) @ Ycat(256x12)
__global__ __launch_bounds__(256) void k_sB(const _Float16* __restrict__ Yg,
                    const _Float16* __restrict__ A2_g,
                    float* __restrict__ xfr, float* __restrict__ xfi) {
    __shared__ _Float16 Ys[28][136];   // rows 0..23 valid; 24..27 junk (read-but-discarded)
    int bc = blockIdx.x;
    int tid = threadIdx.x;
    int wave = tid >> 6, lane = tid & 63;
    int l15 = lane & 15, quad = lane >> 4;
    const _Float16* base = Yg + (size_t)bc * 3072;   // [x][t], t fastest
    for (int i = tid; i < 3072; i += 256) {
        int x = i / 24, t = i - x*24;
        Ys[t][x] = base[i];
    }
    __syncthreads();
    if (wave < 3) {
        f32x4 acc = {0.f,0.f,0.f,0.f};
        #pragma unroll
        for (int q = 0; q < 8; q++) {
            f16x8 a = *(const f16x8*)&A2_g[(size_t)(wave*16 + l15)*256 + q*32 + quad*8];
            const _Float16* brow = (q < 4) ? &Ys[l15][q*32 + quad*8]
                                           : &Ys[12 + l15][(q-4)*32 + quad*8];
            f16x8 bfr = *(const f16x8*)brow;
            acc = __builtin_amdgcn_mfma_f32_16x16x32_f16(a, bfr, acc, 0, 0, 0);
        }
        if (l15 < 12) {
            #pragma unroll
            for (int r = 0; r < 4; r++) {
                int m = wave*16 + quad*4 + r;
                if (m < 24) xfr[(size_t)bc * NMODE + m*12 + l15] = acc[r];
                else        xfi[(size_t)bc * NMODE + (m-24)*12 + l15] = acc[r];
            }
        }
    }
}

// ---------------- S3: mode mixing (complex 64ch -> 64ch), fp32 VALU ----------------
// grid: (Bq, 24), block 256
__global__ __launch_bounds__(256) void k_s3(const float* __restrict__ xfr, const float* __restrict__ xfi,
                    const float* __restrict__ w1r, const float* __restrict__ w1i,
                    const float* __restrict__ w2r, const float* __restrict__ w2i,
                    float* __restrict__ ofr, float* __restrict__ ofi, int layer) {
    __shared__ float ar[64][12], ai[64][12];
    int b = blockIdx.x, kxi = blockIdx.y;
    for (int i = threadIdx.x; i < 64*12; i += 256) {
        int ii = i / 12, ky = i - ii*12;
        size_t idx = (size_t)(b*64 + ii) * NMODE + kxi*12 + ky;
        ar[ii][ky] = xfr[idx];
        ai[ii][ky] = xfi[idx];
    }
    __syncthreads();
    const float *wr, *wi; int kxw;
    if (kxi < 12) { wr = w1r; wi = w1i; kxw = kxi; }
    else          { wr = w2r; wi = w2i; kxw = kxi - 12; }
    size_t lbase = (size_t)layer * 64*64*144 + (size_t)kxw*12;
    for (int o = threadIdx.x; o < 64*12; o += 256) {
        int oo = o / 12, ky = o - oo*12;
        float sr = 0.f, si = 0.f;
        #pragma unroll 4
        for (int i2 = 0; i2 < 64; i2++) {
            float xr = ar[i2][ky], xi2 = ai[i2][ky];
            size_t widx = lbase + (size_t)(i2*64 + oo)*144 + ky;
            float wrr = wr[widx], wii = wi[widx];
            sr += xr*wrr - xi2*wii;
            si += xr*wii + xi2*wrr;
        }
        size_t oidx = (size_t)(b*64 + oo) * NMODE + kxi*12 + ky;
        ofr[oidx] = sr;
        ofi[oidx] = si;
    }
}

// ---------------- S45: inverse-x + fused [pointwise | inverse-y] MFMA + gelu + y-DFT ----
// grid: (128 rows, Bq), block 256. In-place update of x; produces next layer's Yg.
__global__ __launch_bounds__(256) void k_s45(_Float16* __restrict__ xh,
                    const float* __restrict__ ofr, const float* __restrict__ ofi,
                    const _Float16* __restrict__ T1e_g, const _Float16* __restrict__ T1eT_g,
                    const float* __restrict__ T2c, const float* __restrict__ T2s,
                    const float* __restrict__ pw, const float* __restrict__ pwb,
                    _Float16* __restrict__ Yg, int layer) {
    __shared__ _Float16 BsT[128][104];            // [y][k]: 0..63 X, 64..95 spectral; reused as Xn[y][c]
    __shared__ __align__(16) char smem2[64*136*2]; // union: As[64][104] then Ot[64][136]
    __shared__ _Float16 T1eR[32][136];
    __shared__ float t2r[24], t2i[24];
    _Float16 (*As)[104] = (_Float16(*)[104])smem2;
    _Float16 (*Ot)[136] = (_Float16(*)[136])smem2;

    int row = blockIdx.x, b = blockIdx.y;
    int tid = threadIdx.x;
    int wave = tid >> 6, lane = tid & 63;
    int l15 = lane & 15, quad = lane >> 4;

    _Float16* xrow = xh + (size_t)(b*128 + row) * 128 * 64;

    // X tile: coalesced float4 loads, [y][c] -> BsT[y][0..63]
    const float4* xr4 = (const float4*)xrow;
    for (int i = tid; i < 1024; i += 256) {
        int y = i >> 3, seg = i & 7;
        *(float4*)&BsT[y][seg*8] = xr4[i];
    }
    // spectral basis cols: T1eT [y][32] -> BsT[y][64..95]
    const float4* t1tp = (const float4*)T1eT_g;
    for (int i = tid; i < 512; i += 256) {
        int y = i >> 2, seg = i & 3;
        *(float4*)&BsT[y][64 + seg*8] = t1tp[i];
    }
    // T1eR rows for stage A
    const float4* t1p = (const float4*)T1e_g;
    for (int i = tid; i < 512; i += 256) {
        int t = i >> 4, seg = i & 15;
        *(float4*)&T1eR[t][seg*8] = t1p[i];
    }
    // W -> As cols 0..63
    for (int i = tid; i < 4096; i += 256)
        As[i >> 6][i & 63] = (_Float16)pw[(size_t)layer * 4096 + i];
    // zero pad cols 88..95
    for (int i = tid; i < 512; i += 256)
        As[i >> 3][88 + (i & 7)] = (_Float16)0.f;
    if (tid < 24) {
        t2r[tid] = T2c[tid * 128 + row];
        t2i[tid] = T2s[tid * 128 + row];
    }
    __syncthreads();

    // inverse-x at x=row: G[o][ky] = sum_kx of[o,kx,ky] * e^{+i 2pi kx row/128}
    for (int i = tid; i < 768; i += 256) {
        int o = i / 12, ky = i - o*12;
        const float* pr = ofr + (size_t)(b*64 + o) * NMODE + ky;
        const float* pi = ofi + (size_t)(b*64 + o) * NMODE + ky;
        float sr = 0.f, si = 0.f;
        #pragma unroll
        for (int k = 0; k < 24; k++) {
            float a = pr[k*12], bb = pi[k*12];
            float cc = t2r[k], ss = t2i[k];
            sr += a*cc - bb*ss;
            si += a*ss + bb*cc;
        }
        float sc = ((ky == 0) ? 1.f : 2.f) * (1.f/16384.f);
        As[o][64 + ky] = (_Float16)(sr * sc);
        As[o][76 + ky] = (_Float16)(si * sc);
    }
    __syncthreads();

    // main GEMM: out(64o x 128y) = As(64x96) @ B(96x128), K-tiles q=0..2
    f16x8 af3[3];
    #pragma unroll
    for (int q = 0; q < 3; q++)
        af3[q] = *(const f16x8*)&As[wave*16 + l15][q*32 + quad*8];
    float pb[4];
    #pragma unroll
    for (int r = 0; r < 4; r++)
        pb[r] = pwb[layer*64 + wave*16 + quad*4 + r];
    f32x4 acc[8];
    #pragma unroll
    for (int nt = 0; nt < 8; nt++) {
        acc[nt].x = 0.f; acc[nt].y = 0.f; acc[nt].z = 0.f; acc[nt].w = 0.f;
        #pragma unroll
        for (int q = 0; q < 3; q++) {
            f16x8 bfr = *(const f16x8*)&BsT[nt*16 + l15][q*32 + quad*8];
            acc[nt] = __builtin_amdgcn_mfma_f32_16x16x32_f16(af3[q], bfr, acc[nt], 0, 0, 0);
        }
    }
    __syncthreads();   // all BsT/As reads complete before overwrite

    // gelu; write Xn (=BsT, [y][c]) and Ot ([o][y])
    #pragma unroll
    for (int nt = 0; nt < 8; nt++) {
        int y = nt*16 + l15;
        #pragma unroll
        for (int r = 0; r < 4; r++) {
            int o = wave*16 + quad*4 + r;
            float v = acc[nt][r] + pb[r];
            float g = 0.5f * v * (1.f + erff(v * 0.70710678118654752f));
            _Float16 h = (_Float16)g;
            BsT[y][o] = h;
            Ot[o][y] = h;
        }
    }
    __syncthreads();

    epilogue_store(BsT, Ot, T1eR, xrow, Yg, b, row, tid);
}

// ---------------- final: layer-3 at 4 points + fc1 + fc2 + bilinear ----------------
// grid: Bq, block 256 (tid -> point=tid>>6, o=tid&63)
__global__ __launch_bounds__(256) void k_final(const _Float16* __restrict__ x,
                    const float* __restrict__ ofr, const float* __restrict__ ofi,
                    const float* __restrict__ pw, const float* __restrict__ pwb,
                    const float* __restrict__ fc1w, const float* __restrict__ fc1b,
                    const float* __restrict__ fc2w, const float* __restrict__ fc2b,
                    const float* __restrict__ xyt, const int* __restrict__ Lx, const int* __restrict__ Ly,
                    float* __restrict__ out) {
    __shared__ float y4[4][64];
    __shared__ float hh[4][129];
    __shared__ int   pxy[4][2];
    __shared__ float wxy[2];
    int b = blockIdx.x;
    if (threadIdx.x == 0) {
        float Lxf = fmaxf((float)Lx[0], 1e-6f);
        float Lyf = fmaxf((float)Ly[0], 1e-6f);
        float x01 = fminf(fmaxf(xyt[b*3 + 0] / Lxf, 0.f), 1.f);
        float y01 = fminf(fmaxf(xyt[b*3 + 1] / Lyf, 0.f), 1.f);
        float gx = x01 * (NXg - 1), gy = y01 * (NYg - 1);
        int x0 = (int)floorf(gx), y0 = (int)floorf(gy);
        int x1 = min(x0 + 1, NXg - 1), y1 = min(y0 + 1, NYg - 1);
        wxy[0] = gx - (float)x0;
        wxy[1] = gy - (float)y0;
        pxy[0][0] = x0; pxy[0][1] = y0;
        pxy[1][0] = x1; pxy[1][1] = y0;
        pxy[2][0] = x0; pxy[2][1] = y1;
        pxy[3][0] = x1; pxy[3][1] = y1;
    }
    __syncthreads();
    {
        int p = threadIdx.x >> 6, o = threadIdx.x & 63;
        int px = pxy[p][0], py = pxy[p][1];
        float gkr[12], gki[12];
        #pragma unroll
        for (int ky = 0; ky < 12; ky++) { gkr[ky] = 0.f; gki[ky] = 0.f; }
        const float* obr = ofr + (size_t)(b*64 + o) * NMODE;
        const float* obi = ofi + (size_t)(b*64 + o) * NMODE;
        for (int kxi = 0; kxi < 24; kxi++) {
            int kx = (kxi < 12) ? kxi : (104 + kxi);
            int m = (kx * px) & 127;
            float th = (float)m * PI2_128;
            float ss, cc; sincosf(th, &ss, &cc);
            #pragma unroll
            for (int ky = 0; ky < 12; ky++) {
                float a = obr[kxi*12 + ky], bb = obi[kxi*12 + ky];
                gkr[ky] += a*cc - bb*ss;
                gki[ky] += a*ss + bb*cc;
            }
        }
        float sp = gkr[0];
        #pragma unroll
        for (int ky = 1; ky < 12; ky++) {
            int m = (ky * py) & 127;
            float th = (float)m * PI2_128;
            float ss, cc; sincosf(th, &ss, &cc);
            sp += 2.f * (gkr[ky]*cc - gki[ky]*ss);
        }
        float s = 0.f;
        const _Float16* xb = x + ((size_t)(b*128 + px)*128 + py)*64;
        #pragma unroll 4
        for (int c = 0; c < 64; c++)
            s += pw[3*4096 + o*64 + c] * (float)xb[c];
        y4[p][o] = sp * (1.f/16384.f) + s + pwb[3*64 + o];
    }
    __syncthreads();
    for (int i = threadIdx.x; i < 512; i += 256) {
        int p = i >> 7, f = i & 127;
        float s = fc1b[f];
        #pragma unroll 4
        for (int w = 0; w < 64; w++) s += y4[p][w] * fc1w[w*128 + f];
        hh[p][f] = 0.5f * s * (1.f + erff(s * 0.70710678118654752f));
    }
    __syncthreads();
    if (threadIdx.x < 3) {
        int o3 = threadIdx.x;
        float f4[4];
        #pragma unroll
        for (int p = 0; p < 4; p++) {
            float s = fc2b[o3];
            #pragma unroll 4
            for (int f = 0; f < 128; f++) s += hh[p][f] * fc2w[f*3 + o3];
            f4[p] = s;
        }
        float wx = wxy[0], wy = wxy[1];
        float top = f4[0]*(1.f - wx) + f4[1]*wx;
        float bot = f4[2]*(1.f - wx) + f4[3]*wx;
        out[b*3 + o3] = top*(1.f - wy) + bot*wy;
    }
}

extern "C" void kernel_launch(void* const* d_in, const int* in_sizes, int n_in,
                              void* d_out, int out_size, void* d_ws, size_t ws_size,
                              hipStream_t stream) {
    const float* xyt    = (const float*)d_in[0];
    const float* obs_c  = (const float*)d_in[1];
    const float* obs_v  = (const float*)d_in[2];
    const float* xg     = (const float*)d_in[3];
    const float* yg     = (const float*)d_in[4];
    const float* fc0w   = (const float*)d_in[5];
    const float* fc0b   = (const float*)d_in[6];
    const float* w1r    = (const float*)d_in[7];
    const float* w1i    = (const float*)d_in[8];
    const float* w2r    = (const float*)d_in[9];
    const float* w2i    = (const float*)d_in[10];
    const float* pww    = (const float*)d_in[11];
    const float* pwb    = (const float*)d_in[12];
    const float* fc1w   = (const float*)d_in[13];
    const float* fc1b   = (const float*)d_in[14];
    const float* fc2w   = (const float*)d_in[15];
    const float* fc2b   = (const float*)d_in[16];
    const int*   nb     = (const int*)d_in[17];
    const int*   siy    = (const int*)d_in[18];
    const int*   six    = (const int*)d_in[19];
    const int*   Lx     = (const int*)d_in[20];
    const int*   Ly     = (const int*)d_in[21];
    float* out = (float*)d_out;

    float* W = (float*)d_ws;
    float* T2c = W + OFF_T2C;
    float* T2s = W + OFF_T2S;
    float* val = W + OFF_VAL;
    float* cnt = W + OFF_CNT;
    float* xfr = W + OFF_XFR;
    float* xfi = W + OFF_XFI;
    float* ofr = W + OFF_OFR;
    float* ofi = W + OFF_OFI;
    _Float16* Hbase = (_Float16*)(W + F32_END);
    _Float16* T1e_g  = Hbase + H_T1E;
    _Float16* T1eT_g = Hbase + H_T1ET;
    _Float16* A2_g   = Hbase + H_A2;
    _Float16* Yg     = Hbase + H_YG;
    _Float16* xh     = Hbase + H_X;

    // zero scatter accumulators (val+cnt contiguous)
    hipMemsetAsync(val, 0, (size_t)2 * Bq * Pg * sizeof(float), stream);

    k_tables<<<48, 256, 0, stream>>>(T2c, T2s, T1e_g, T1eT_g, A2_g);
    k_scatter<<<64, 64, 0, stream>>>(xyt, obs_c, obs_v, nb, siy, six, val, cnt);
    k_fc0y<<<dim3(128, Bq), 256, 0, stream>>>(val, cnt, xg, yg, fc0w, fc0b, T1e_g, xh, Yg);

    for (int l = 0; l < 3; l++) {
        k_sB<<<Bq*Wd, 256, 0, stream>>>(Yg, A2_g, xfr, xfi);
        k_s3<<<dim3(Bq, 24), 256, 0, stream>>>(xfr, xfi, w1r, w1i, w2r, w2i, ofr, ofi, l);
        k_s45<<<dim3(128, Bq), 256, 0, stream>>>(xh, ofr, ofi, T1e_g, T1eT_g, T2c, T2s, pww, pwb, Yg, l);
    }
    // layer 3: spectral coefficients only; evaluate at 4 points in k_final
    k_sB<<<Bq*Wd, 256, 0, stream>>>(Yg, A2_g, xfr, xfi);
    k_s3<<<dim3(Bq, 24), 256, 0, stream>>>(xfr, xfi, w1r, w1i, w2r, w2i, ofr, ofi, 3);
    k_final<<<Bq, 256, 0, stream>>>(xh, ofr, ofi, pww, pwb, fc1w, fc1b, fc2w, fc2b,
                                    xyt, Lx, Ly, out);
}